// Round 13
// baseline (275.443 us; speedup 1.0000x reference)
//
#include <hip/hip_runtime.h>
#include <hip/hip_bf16.h>
#include <math.h>

#define IN_CH 128
#define HID 64
#define OUT_CH 40
#define NBUCK 1024
#define NBSHIFT 10
#define CAP2 3125     // bins2 slots per bucket (2x mean 1563); 1024*3125*4B = 12.8MB
#define CAPL 2560     // LDS records per bucket in k_csr (~25 sigma above mean)

typedef const __hip_bfloat16* bf16p;
typedef __attribute__((ext_vector_type(8))) short bf16x8;
typedef __attribute__((ext_vector_type(4))) float f32x4;
typedef __attribute__((ext_vector_type(8))) float f32x8;

// bf16 -> f32 is exact: shift into the high half
__device__ __forceinline__ f32x8 cvt8(bf16x8 v) {
    f32x8 o;
    #pragma unroll
    for (int j = 0; j < 8; ++j) {
        unsigned int bits = ((unsigned int)(unsigned short)v[j]) << 16;
        o[j] = __uint_as_float(bits);
    }
    return o;
}

__device__ __forceinline__ bf16x8 pack8(f32x8 v) {
    bf16x8 o;
    #pragma unroll
    for (int j = 0; j < 8; ++j) {
        __hip_bfloat16 b = __float2bfloat16(v[j]);
        o[j] = *reinterpret_cast<short*>(&b);
    }
    return o;
}

// exact bucket of column c: b s.t. b*N <= c*1024 < (b+1)*N. Float approx + exact
// 64-bit-mul fixup (no divide; fixup loops run <=1 iteration).
__device__ __forceinline__ int bucket_of(int c, int N, float invNB) {
    int b = (int)((float)c * invNB);
    long long cB = (long long)c << NBSHIFT;
    while ((long long)(b + 1) * N <= cB) ++b;
    while (b > 0 && (long long)b * N > cB) --b;
    return b;
}

// ---- fused flag detection + weight conversion + bincnt2 zeroing (1 block).
__global__ __launch_bounds__(256) void k_detectconv(const void* x, const void* ei,
        int* flags, const void* W1, const void* b1, const void* W2, const void* b2,
        float* wf, int* bincnt2) {
    __shared__ int s_f32, s_hi;
    if (threadIdx.x == 0) { s_f32 = 0; s_hi = 0; }
    __syncthreads();
    const __hip_bfloat16* xb = (const __hip_bfloat16*)x;
    const int* ii = (const int*)ei;
    int lf = 0, lh = 0;
    for (int i = threadIdx.x; i < 4096; i += 256) {
        float f = __bfloat162float(xb[i]);
        if (!(fabsf(f) <= 1e4f)) lf = 1;       // huge/NaN -> buffer is really f32
        lh |= ii[2 * i + 1];                    // int64 high words are all zero
    }
    if (lf) atomicOr(&s_f32, 1);
    if (lh) atomicOr(&s_hi, 1);
    for (int i = threadIdx.x; i < NBUCK; i += 256) bincnt2[i] = 0;
    __syncthreads();
    const int isF32 = s_f32 ? 1 : 0;
    if (threadIdx.x == 0) {
        flags[0] = isF32;
        flags[1] = (s_hi == 0) ? 1 : 0;
        flags[2] = 0;
    }
    for (int i = threadIdx.x; i < 10856; i += 256) {
        const void* src; int off;
        if (i < 8192)       { src = W1; off = i; }
        else if (i < 8256)  { src = b1; off = i - 8192; }
        else if (i < 10816) { src = W2; off = i - 8256; }
        else                { src = b2; off = i - 10816; }
        wf[i] = isF32 ? ((const float*)src)[off]
                      : __bfloat162float(((bf16p)src)[off]);
    }
}

// ---- Partition edges into 1024 c-contiguous buckets. No per-edge global atomics.
//      Records packed to 4 B: (r << 7) | (c - nlo_bucket). Chunk 2048 -> 782
//      blocks (was 391: only ~1.5 blocks/CU, poor coverage for LDS-atomic pipe).
__global__ __launch_bounds__(512) void k_bin2(const int* ei, const int* flags,
        int* bincnt2, unsigned int* bins2, int E, int N, float invNB) {
    __shared__ int cnt[NBUCK], base[NBUCK];
    for (int i = threadIdx.x; i < NBUCK; i += 512) cnt[i] = 0;
    __syncthreads();
    const int i64 = flags[1];
    const int e0 = blockIdx.x * 2048;
    const int e1 = min(e0 + 2048, E);
    int e = e0 + threadIdx.x;
    for (; e + 3 * 512 < e1; e += 4 * 512) {
        int c0 = i64 ? ei[2 * (E + e)]        : ei[E + e];
        int c1 = i64 ? ei[2 * (E + e + 512)]  : ei[E + e + 512];
        int c2 = i64 ? ei[2 * (E + e + 1024)] : ei[E + e + 1024];
        int c3 = i64 ? ei[2 * (E + e + 1536)] : ei[E + e + 1536];
        atomicAdd(&cnt[bucket_of(c0, N, invNB)], 1);
        atomicAdd(&cnt[bucket_of(c1, N, invNB)], 1);
        atomicAdd(&cnt[bucket_of(c2, N, invNB)], 1);
        atomicAdd(&cnt[bucket_of(c3, N, invNB)], 1);
    }
    for (; e < e1; e += 512) {
        int c = i64 ? ei[2 * (E + e)] : ei[E + e];
        atomicAdd(&cnt[bucket_of(c, N, invNB)], 1);
    }
    __syncthreads();
    for (int i = threadIdx.x; i < NBUCK; i += 512) {
        int v = cnt[i];
        base[i] = v ? atomicAdd(&bincnt2[i], v) : 0;
        cnt[i] = 0;   // reuse as within-block cursor
    }
    __syncthreads();
    for (e = e0 + threadIdx.x; e < e1; e += 512) {  // chunk is L2-hot now
        int r, c;
        if (i64) { r = ei[2 * e]; c = ei[2 * (E + e)]; }
        else     { r = ei[e];     c = ei[E + e]; }
        int b = bucket_of(c, N, invNB);
        int nlo = (int)(((long long)b * N + NBUCK - 1) >> NBSHIFT);
        int slot = base[b] + atomicAdd(&cnt[b], 1);
        if (slot < CAP2)   // memory safety; never triggers at 2x margin
            bins2[(size_t)b * CAP2 + slot] =
                ((unsigned int)r << 7) | (unsigned int)(c - nlo);
    }
}

// ---- Per-bucket CSR finalize, entirely in LDS (no global atomics). Scan via
//      shfl wave-scan (2 barriers instead of 16 LDS ping-pong barriers).
__global__ __launch_bounds__(256) void k_csr(const unsigned int* bins2, const int* bincnt2,
        int* rowstart, float* dinv, int* erow, int N) {
    __shared__ unsigned int rc[CAPL];              // 10 KB
    __shared__ int sdeg[256], lcur[256], red[256], wsums[4];
    const int s = blockIdx.x;
    const int tid = threadIdx.x;
    const int lane = tid & 63;
    const int wv = tid >> 6;
    // gb = sum_{j<s} min(bincnt2[j], CAPL)
    int part = 0;
    for (int j = tid; j < s; j += 256) part += min(bincnt2[j], CAPL);
    red[tid] = part;
    __syncthreads();
    for (int o = 128; o > 0; o >>= 1) {
        if (tid < o) red[tid] += red[tid + o];
        __syncthreads();
    }
    const int gb = red[0];
    const int nlo = (int)(((long long)s * N + NBUCK - 1) >> NBSHIFT);
    const int nhi = (int)(((long long)(s + 1) * N + NBUCK - 1) >> NBSHIFT);
    const int width = nhi - nlo;                   // <= 98 for N=100000
    const int cnt = min(bincnt2[s], CAPL);

    for (int i = tid; i < cnt; i += 256) rc[i] = bins2[(size_t)s * CAP2 + i];
    sdeg[tid] = 0;
    __syncthreads();
    for (int i = tid; i < cnt; i += 256) {
        int j = (int)(rc[i] & 127u);
        if (j < width) atomicAdd(&sdeg[j], 1);
    }
    __syncthreads();
    int my = sdeg[tid];
    // inclusive scan: shfl wave-scan + cross-wave offsets
    int v = my;
    #pragma unroll
    for (int off = 1; off < 64; off <<= 1) {
        int t = __shfl_up(v, off, 64);
        if (lane >= off) v += t;
    }
    if (lane == 63) wsums[wv] = v;
    __syncthreads();
    int add = 0;
    #pragma unroll
    for (int k = 0; k < 4; ++k) if (k < wv) add += wsums[k];
    int excl = v + add - my;
    lcur[tid] = excl;
    if (tid < width) {
        rowstart[nlo + tid] = gb + excl;
        dinv[nlo + tid] = rsqrtf((float)my + 1.0f);   // +1 = self-loop
    }
    if (s == NBUCK - 1 && tid == 0) rowstart[N] = gb + cnt;
    __syncthreads();
    for (int i = tid; i < cnt; i += 256) {
        unsigned int vv = rc[i];
        int j = (int)(vv & 127u);
        if (j < width) {
            int pos = atomicAdd(&lcur[j], 1);
            erow[gb + pos] = (int)(vv >> 7);   // random 4B within ~6KB L2 region
        }
    }
}

// ---- GEMM1 via MFMA (HW-verified R0), storing PRE-SCALED features:
//      h1s[n][c] = bf16( (sum_k x[n][k]*W1[k][c]) * dinv[n] ).
//      A: lane l, elem j -> A[l&15][(l>>4)*8 + j]
//      B: lane l, elem j -> B[(l>>4)*8 + j][l&15]
//      C: lane l, reg  q -> C[(l>>4)*4 + q][l&15]
__global__ __launch_bounds__(256) void k_gemm1_mfma(const void* x, const float* W1f,
        const float* dinv, __hip_bfloat16* h1s, const int* flags, int N) {
    __shared__ __align__(16) unsigned short wT[HID][IN_CH];   // W1^T, bf16 bits, 16 KB
    for (int i = threadIdx.x; i < IN_CH * HID; i += 256) {
        int k = i >> 6, c = i & 63;
        __hip_bfloat16 b = __float2bfloat16(W1f[i]);
        wT[c][k] = *reinterpret_cast<unsigned short*>(&b);
    }
    __syncthreads();

    const int isF32 = flags[0];
    const int lane = threadIdx.x & 63;
    const int wid  = threadIdx.x >> 6;
    const int r = lane & 15;     // A row / B col / C col within tile
    const int g = lane >> 4;     // k-group

    bf16x8 bfr[4][4];
    #pragma unroll
    for (int nt = 0; nt < 4; ++nt)
        #pragma unroll
        for (int ks = 0; ks < 4; ++ks)
            bfr[nt][ks] = *(const bf16x8*)&wT[nt * 16 + r][ks * 32 + g * 8];

    const int tiles = (N + 15) >> 4;
    for (int t = blockIdx.x * 4 + wid; t < tiles; t += gridDim.x * 4) {
        const int row0 = t * 16;
        int arow = row0 + r; if (arow >= N) arow = N - 1;   // clamp (stores guarded)
        bf16x8 afr[4];
        if (!isF32) {
            const unsigned short* xr = (const unsigned short*)x + (size_t)arow * IN_CH;
            #pragma unroll
            for (int ks = 0; ks < 4; ++ks)
                afr[ks] = *(const bf16x8*)&xr[ks * 32 + g * 8];
        } else {
            const float* xr = (const float*)x + (size_t)arow * IN_CH;
            #pragma unroll
            for (int ks = 0; ks < 4; ++ks) {
                f32x4 a0 = *(const f32x4*)&xr[ks * 32 + g * 8];
                f32x4 a1 = *(const f32x4*)&xr[ks * 32 + g * 8 + 4];
                #pragma unroll
                for (int j = 0; j < 4; ++j) {
                    __hip_bfloat16 b0 = __float2bfloat16(a0[j]);
                    __hip_bfloat16 b1v = __float2bfloat16(a1[j]);
                    afr[ks][j]     = *reinterpret_cast<short*>(&b0);
                    afr[ks][j + 4] = *reinterpret_cast<short*>(&b1v);
                }
            }
        }
        f32x4 acc[4] = {};
        #pragma unroll
        for (int ks = 0; ks < 4; ++ks)
            #pragma unroll
            for (int nt = 0; nt < 4; ++nt)
                acc[nt] = __builtin_amdgcn_mfma_f32_16x16x32_bf16(afr[ks], bfr[nt][ks],
                                                                  acc[nt], 0, 0, 0);
        #pragma unroll
        for (int q = 0; q < 4; ++q) {
            int rr = row0 + g * 4 + q;
            if (rr < N) {
                float dv = dinv[rr];
                #pragma unroll
                for (int nt = 0; nt < 4; ++nt)
                    h1s[(size_t)rr * HID + nt * 16 + r] =
                        __float2bfloat16(acc[nt][q] * dv);
            }
        }
    }
}

// ---- Aggregation 1 on pre-scaled features: pure gather-SUM.
//      g = relu(d*(h1s[w] + sum_e h1s[r]) + b1); stores gs = g*d.
__global__ __launch_bounds__(256) void k_agg1(const int* rowstart, const int* erow,
        const __hip_bfloat16* h1s, const float* dinv, const float* b1f,
        __hip_bfloat16* gs, int N) {
    const int lane = threadIdx.x & 63;
    const int sub = lane >> 3;
    const int co  = lane & 7;
    const f32x4 b1a = *(const f32x4*)&b1f[co * 8];
    const f32x4 b1b = *(const f32x4*)&b1f[co * 8 + 4];
    const int wstride = (gridDim.x * 256) >> 6;
    for (int w = (blockIdx.x * 256 + threadIdx.x) >> 6; w < N; w += wstride) {
        int s0 = __builtin_amdgcn_readfirstlane(rowstart[w]);
        int s1 = __builtin_amdgcn_readfirstlane(rowstart[w + 1]);
        float d = dinv[w];
        bf16x8 sv = *(const bf16x8*)&h1s[(size_t)w * HID + co * 8];
        f32x8 acc = {};
        int i = s0 + sub;
        for (; i + 8 < s1; i += 16) {
            int r0 = erow[i], r1 = erow[i + 8];
            f32x8 v0 = cvt8(*(const bf16x8*)&h1s[(size_t)r0 * HID + co * 8]);
            f32x8 v1 = cvt8(*(const bf16x8*)&h1s[(size_t)r1 * HID + co * 8]);
            #pragma unroll
            for (int j = 0; j < 8; ++j) acc[j] += v0[j] + v1[j];
        }
        if (i < s1) {
            int r0 = erow[i];
            f32x8 v0 = cvt8(*(const bf16x8*)&h1s[(size_t)r0 * HID + co * 8]);
            #pragma unroll
            for (int j = 0; j < 8; ++j) acc[j] += v0[j];
        }
        #pragma unroll
        for (int j = 0; j < 8; ++j) {
            acc[j] += __shfl_xor(acc[j], 8);
            acc[j] += __shfl_xor(acc[j], 16);
            acc[j] += __shfl_xor(acc[j], 32);
        }
        if (sub == 0) {
            f32x8 sf = cvt8(sv);
            f32x8 gv;
            #pragma unroll
            for (int j = 0; j < 4; ++j) {
                float ga = fmaxf(fmaf(d, sf[j] + acc[j], b1a[j]), 0.f);
                float gb = fmaxf(fmaf(d, sf[j + 4] + acc[j + 4], b1b[j]), 0.f);
                gv[j]     = ga * d;     // pre-scale for agg2's gather
                gv[j + 4] = gb * d;
            }
            *(bf16x8*)&gs[(size_t)w * HID + co * 8] = pack8(gv);
        }
    }
}

// ---- GEMM2 moved BEFORE aggregation 2 (it commutes): ts = gs @ W2, stored as
//      tight 40-ch bf16 rows (80 B). Shrinks agg2's gather table 12.8 -> 8 MB;
//      the aggregation passes are fabric-service-bound, so bytes = time.
__global__ __launch_bounds__(256) void k_gemm2t(const __hip_bfloat16* gs,
        const float* W2f, __hip_bfloat16* ts, int N) {
    __shared__ __align__(16) unsigned short w2T[48][HID];   // W2^T padded, bf16 bits, 6 KB
    for (int i = threadIdx.x; i < 48 * HID; i += 256) {
        int c = i >> 6, k = i & 63;
        float v = (c < OUT_CH) ? W2f[k * OUT_CH + c] : 0.f;
        __hip_bfloat16 b = __float2bfloat16(v);
        w2T[c][k] = *reinterpret_cast<unsigned short*>(&b);
    }
    __syncthreads();

    const int lane = threadIdx.x & 63;
    const int wid  = threadIdx.x >> 6;
    const int r = lane & 15;
    const int gq = lane >> 4;

    bf16x8 bfr[3][2];
    #pragma unroll
    for (int nt = 0; nt < 3; ++nt)
        #pragma unroll
        for (int ks = 0; ks < 2; ++ks)
            bfr[nt][ks] = *(const bf16x8*)&w2T[nt * 16 + r][ks * 32 + gq * 8];

    const int tiles = (N + 15) >> 4;
    for (int t = blockIdx.x * 4 + wid; t < tiles; t += gridDim.x * 4) {
        const int row0 = t * 16;
        int arow = row0 + r; if (arow >= N) arow = N - 1;
        const unsigned short* sr = (const unsigned short*)gs + (size_t)arow * HID;
        bf16x8 afr[2];
        afr[0] = *(const bf16x8*)&sr[gq * 8];
        afr[1] = *(const bf16x8*)&sr[32 + gq * 8];
        f32x4 acc[3] = {};
        #pragma unroll
        for (int ks = 0; ks < 2; ++ks)
            #pragma unroll
            for (int nt = 0; nt < 3; ++nt)
                acc[nt] = __builtin_amdgcn_mfma_f32_16x16x32_bf16(afr[ks], bfr[nt][ks],
                                                                  acc[nt], 0, 0, 0);
        #pragma unroll
        for (int nt = 0; nt < 3; ++nt) {
            int c = nt * 16 + r;
            #pragma unroll
            for (int q = 0; q < 4; ++q) {
                int rr = row0 + gq * 4 + q;
                if (rr < N && c < OUT_CH)
                    ts[(size_t)rr * OUT_CH + c] = __float2bfloat16(acc[nt][q]);
            }
        }
    }
}

// ---- Aggregation 2 on 40-ch ts rows (80 B gathers): out = d*(ts[w] + sum_e
//      ts[r]) + b2, f32 out. Lane = (sub 0..7, co 0..7); co<5 carries channels.
__global__ __launch_bounds__(256) void k_agg2f(const int* rowstart, const int* erow,
        const __hip_bfloat16* ts, const float* dinv, const float* b2f,
        float* out, int N) {
    const int lane = threadIdx.x & 63;
    const int sub = lane >> 3;
    const int co  = lane & 7;
    const bool act = (co < 5);
    f32x4 b2a = {}, b2b = {};
    if (act) {
        b2a = *(const f32x4*)&b2f[co * 8];
        b2b = *(const f32x4*)&b2f[co * 8 + 4];
    }
    const int wstride = (gridDim.x * 256) >> 6;
    for (int w = (blockIdx.x * 256 + threadIdx.x) >> 6; w < N; w += wstride) {
        int s0 = __builtin_amdgcn_readfirstlane(rowstart[w]);
        int s1 = __builtin_amdgcn_readfirstlane(rowstart[w + 1]);
        float d = dinv[w];
        bf16x8 sv = {};
        if (act) sv = *(const bf16x8*)&ts[(size_t)w * OUT_CH + co * 8];
        f32x8 acc = {};
        int i = s0 + sub;
        for (; i + 8 < s1; i += 16) {
            int r0 = erow[i], r1 = erow[i + 8];
            if (act) {
                f32x8 v0 = cvt8(*(const bf16x8*)&ts[(size_t)r0 * OUT_CH + co * 8]);
                f32x8 v1 = cvt8(*(const bf16x8*)&ts[(size_t)r1 * OUT_CH + co * 8]);
                #pragma unroll
                for (int j = 0; j < 8; ++j) acc[j] += v0[j] + v1[j];
            }
        }
        if (i < s1) {
            int r0 = erow[i];
            if (act) {
                f32x8 v0 = cvt8(*(const bf16x8*)&ts[(size_t)r0 * OUT_CH + co * 8]);
                #pragma unroll
                for (int j = 0; j < 8; ++j) acc[j] += v0[j];
            }
        }
        // shfl_xor over lane bits 3..5 (sub); co bits 0..2 preserved
        #pragma unroll
        for (int j = 0; j < 8; ++j) {
            acc[j] += __shfl_xor(acc[j], 8);
            acc[j] += __shfl_xor(acc[j], 16);
            acc[j] += __shfl_xor(acc[j], 32);
        }
        if (sub == 0 && act) {
            f32x8 sf = cvt8(sv);
            f32x8 ov;
            #pragma unroll
            for (int j = 0; j < 4; ++j) {
                ov[j]     = fmaf(d, sf[j] + acc[j], b2a[j]);
                ov[j + 4] = fmaf(d, sf[j + 4] + acc[j + 4], b2b[j]);
            }
            *(f32x8*)&out[(size_t)w * OUT_CH + co * 8] = ov;
        }
    }
}

extern "C" void kernel_launch(void* const* d_in, const int* in_sizes, int n_in,
                              void* d_out, int out_size, void* d_ws, size_t ws_size,
                              hipStream_t stream) {
    const void* x  = d_in[0];
    const void* ei = d_in[1];
    const void* W1 = d_in[2];
    const void* b1 = d_in[3];
    const void* W2 = d_in[4];
    const void* b2 = d_in[5];
    const int N = in_sizes[0] / IN_CH;   // 100000
    const int E = in_sizes[1] / 2;       // 1600000
    const int* eii = (const int*)ei;

    // ---- workspace layout (4-byte units). bins2 (12.8 MB) and ts (8 MB) both
    //      alias h1s: bins2 dead after k_csr (before gemm1 writes h1s); h1s dead
    //      after k_agg1 (before gemm2t writes ts).
    float* ws = (float*)d_ws;
    size_t off = 16;
    int*   flags    = (int*)ws;
    int*   bincnt2  = (int*)ws + off;            off += NBUCK;
    float* dinv     = ws + off;                  off += N;
    float* wf       = ws + off;                  off += 10880;
    int*   rowstart = (int*)ws + off;            off += N + 1;
    off = (off + 255) & ~(size_t)255;
    int*   erow     = (int*)ws + off;            off += E;
    off = (off + 255) & ~(size_t)255;
    __hip_bfloat16* h1s = (__hip_bfloat16*)(ws + off);     off += (size_t)N * HID / 2;
    __hip_bfloat16* gsb = (__hip_bfloat16*)(ws + off);     off += (size_t)N * HID / 2;
    unsigned int* bins2 = (unsigned int*)h1s;    // 12.8 MB, dead after k_csr
    __hip_bfloat16* ts  = h1s;                   // 8 MB, written after h1s dies

    k_detectconv<<<1, 256, 0, stream>>>(x, ei, flags, W1, b1, W2, b2, wf, bincnt2);

    float invNB = (float)NBUCK / (float)N;
    int nbin = (E + 2047) / 2048;        // 782 blocks x 512 threads
    k_bin2<<<nbin, 512, 0, stream>>>(eii, flags, bincnt2, bins2, E, N, invNB);
    k_csr<<<NBUCK, 256, 0, stream>>>(bins2, bincnt2, rowstart, dinv, erow, N);

    int tiles = (N + 15) / 16;
    int g1 = (tiles + 7) / 8;           // 4 waves/block, 2 tiles/wave
    k_gemm1_mfma<<<g1, 256, 0, stream>>>(x, wf, dinv, h1s, flags, N);

    k_agg1<<<4096, 256, 0, stream>>>(rowstart, erow, h1s, dinv, wf + 8192, gsb, N);
    k_gemm2t<<<g1, 256, 0, stream>>>(gsb, wf + 8256, ts, N);
    k_agg2f<<<4096, 256, 0, stream>>>(rowstart, erow, ts, dinv, wf + 10816,
                                      (float*)d_out, N);
}